// Round 1
// baseline (597.057 us; speedup 1.0000x reference)
//
#include <hip/hip_runtime.h>

#define NVOX 400000
#define K27 27
#define EPS_ 1e-5f

typedef short short8 __attribute__((ext_vector_type(8)));
typedef float floatx4 __attribute__((ext_vector_type(4)));
typedef unsigned int uintx4 __attribute__((ext_vector_type(4)));

// round-to-nearest-even fp32 -> bf16, packed pair (a low 16, b high 16)
__device__ __forceinline__ unsigned int pack2bf(float a, float b) {
    unsigned int ua = __builtin_bit_cast(unsigned int, a);
    unsigned int ub = __builtin_bit_cast(unsigned int, b);
    ua += 0x7fffu + ((ua >> 16) & 1u);
    ub += 0x7fffu + ((ub >> 16) & 1u);
    return (ua >> 16) | (ub & 0xffff0000u);
}

// blocks [0, fb): fp32->bf16 feature conversion (32 elems/thread)
// blocks [fb, fb+32): W[k][ci][co] -> wt[k][co][ci] bf16
// block  fb+32: zero the 128 stats accumulators
__global__ void prep_kernel(const float* __restrict__ w,
                            const float* __restrict__ feat,
                            unsigned short* __restrict__ feat_bf,
                            unsigned short* __restrict__ wt,
                            float* __restrict__ sums,
                            int fb) {
    const int b = blockIdx.x;
    const int t = threadIdx.x;
    if (b < fb) {
#pragma unroll
        for (int r = 0; r < 4; ++r) {
            const int i0 = b * 8192 + r * 2048 + t * 8;
            const floatx4* s = (const floatx4*)(feat + i0);
            const floatx4 f0 = s[0], f1 = s[1];
            uintx4 v;
            v[0] = pack2bf(f0[0], f0[1]); v[1] = pack2bf(f0[2], f0[3]);
            v[2] = pack2bf(f1[0], f1[1]); v[3] = pack2bf(f1[2], f1[3]);
            *(uintx4*)(feat_bf + i0) = v;
        }
    } else if (b < fb + 32) {
        for (int g = (b - fb) * 256 + t; g < K27 * 64 * 64; g += 32 * 256) {
            const int k = g >> 12, r = g & 4095, co = r >> 6, ci = r & 63;
            unsigned int u =
                __builtin_bit_cast(unsigned int, w[(k << 12) + (ci << 6) + co]);
            u += 0x7fffu + ((u >> 16) & 1u);
            wt[g] = (unsigned short)(u >> 16);
        }
    } else {
        if (t < 128) sums[t] = 0.0f;
    }
}

// 128 rows x 64 out-ch per block (3125 blocks). 4 waves, wave tile M=32 x
// N=64 -> 2x4 mfma_f32_16x16x32_bf16 per kb (acc 32 AGPR).
//
// R7 structure: BARRIER-FREE k-loop with direct-to-fragment gathers.
// Key fact (verified by the R6 kernel's working LDS path): for
// mfma_f32_16x16x32_bf16, lane (m,q)'s A fragment for sub-tile kb is
// feat[row][kb*32 + q*8 .. +7] -- 16 CONTIGUOUS bytes -- and the B
// fragment is wt[k][nt*16+m][kb*32 + q*8 .. +7], also 16 contiguous
// bytes. So the gather lands directly in MFMA operand registers; the
// LDS tiles (and the 2 barriers per k-iter, 54 per block) were a pure
// pass-through and are deleted. k-loop is manually unrolled by 2 with
// statically-named register sets A/B (scratch-free): fetch of k+1 is
// issued before the MFMAs of k, so LLC gather latency (~500 cyc) hides
// under one full iteration of compute + other waves' progress (waves
// are no longer lockstepped by barriers). Inactive (row,k): load
// skipped (exec-masked), fragment zero-filled. B (8KB/k, shared by all
// 4 waves and all resident blocks) is served by L1/L2; weights total
// 216 KB. LDS keeps only the nmap slice (idx reads = LDS broadcasts)
// and the stats accumulators.
template <bool BF16FEAT>
__launch_bounds__(256)
__global__ void conv_mfma(const float* __restrict__ feat,
                          const unsigned short* __restrict__ feat_bf,
                          const int* __restrict__ nmap,
                          const unsigned short* __restrict__ wt,
                          float* __restrict__ out,
                          float* __restrict__ sums) {
    __shared__ int idx_lds[K27 * 128];  // 13.5 KB
    __shared__ float cstat[128];

    const int tid  = threadIdx.x;
    const int wv   = tid >> 6;
    const int lane = tid & 63;
    const int m    = lane & 15;
    const int q    = lane >> 4;
    const int base = blockIdx.x * 128;

    // ---- preamble: cache nmap[k][base..base+128) in LDS (coalesced)
    for (int j = tid; j < K27 * 128; j += 256)
        idx_lds[j] = nmap[(j >> 7) * NVOX + base + (j & 127)];
    if (tid < 128) cstat[tid] = 0.0f;
    __syncthreads();  // the ONLY barrier before the epilogue

    int row_a[2];
#pragma unroll
    for (int mt = 0; mt < 2; ++mt) row_a[mt] = wv * 32 + mt * 16 + m;

    floatx4 acc[2][4];
#pragma unroll
    for (int mt = 0; mt < 2; ++mt)
#pragma unroll
        for (int nt = 0; nt < 4; ++nt)
            acc[mt][nt] = (floatx4){0.f, 0.f, 0.f, 0.f};

    // fragment sets: A operand [mt][kb], B operand [nt][kb]
    short8 aA[2][2], bA[4][2];
    short8 aB[2][2], bB[4][2];

#define FETCH(aset, bset, kk)                                                 \
    do {                                                                      \
        _Pragma("unroll") for (int mt = 0; mt < 2; ++mt) {                    \
            const int ix = idx_lds[(kk) * 128 + row_a[mt]];                   \
            _Pragma("unroll") for (int kb = 0; kb < 2; ++kb)                  \
                aset[mt][kb] = (short8){0, 0, 0, 0, 0, 0, 0, 0};              \
            if (ix >= 0) {                                                    \
                if (BF16FEAT) {                                               \
                    const unsigned short* ap =                                \
                        feat_bf + (size_t)ix * 64 + q * 8;                    \
                    _Pragma("unroll") for (int kb = 0; kb < 2; ++kb)          \
                        aset[mt][kb] = *(const short8*)(ap + kb * 32);        \
                } else {                                                      \
                    const float* fp = feat + (size_t)ix * 64 + q * 8;         \
                    _Pragma("unroll") for (int kb = 0; kb < 2; ++kb) {        \
                        const floatx4 f0 = *(const floatx4*)(fp + kb * 32);   \
                        const floatx4 f1 =                                    \
                            *(const floatx4*)(fp + kb * 32 + 4);              \
                        uintx4 v;                                             \
                        v[0] = pack2bf(f0[0], f0[1]);                         \
                        v[1] = pack2bf(f0[2], f0[3]);                         \
                        v[2] = pack2bf(f1[0], f1[1]);                         \
                        v[3] = pack2bf(f1[2], f1[3]);                         \
                        aset[mt][kb] = __builtin_bit_cast(short8, v);         \
                    }                                                         \
                }                                                             \
            }                                                                 \
        }                                                                     \
        const unsigned short* bp = wt + (kk) * 4096 + m * 64 + q * 8;         \
        _Pragma("unroll") for (int nt = 0; nt < 4; ++nt)                      \
            _Pragma("unroll") for (int kb = 0; kb < 2; ++kb)                  \
                bset[nt][kb] = *(const short8*)(bp + nt * 1024 + kb * 32);    \
    } while (0)

#define COMPUTE(aset, bset)                                                   \
    do {                                                                      \
        _Pragma("unroll") for (int kb = 0; kb < 2; ++kb)                      \
            _Pragma("unroll") for (int mt = 0; mt < 2; ++mt)                  \
                _Pragma("unroll") for (int nt = 0; nt < 4; ++nt)              \
                    acc[mt][nt] = __builtin_amdgcn_mfma_f32_16x16x32_bf16(    \
                        aset[mt][kb], bset[nt][kb], acc[mt][nt], 0, 0, 0);    \
    } while (0)

    FETCH(aA, bA, 0);
    for (int kk = 0; kk < K27; kk += 2) {
        // iter kk (set A): issue kk+1's gathers first, then compute kk
        if (kk + 1 < K27) FETCH(aB, bB, kk + 1);
        COMPUTE(aA, bA);
        if (kk + 1 >= K27) break;
        // iter kk+1 (set B): issue kk+2's gathers first, then compute kk+1
        if (kk + 2 < K27) FETCH(aA, bA, kk + 2);
        COMPUTE(aB, bB);
    }
#undef FETCH
#undef COMPUTE

    // epilogue: store (C/D: col=lane&15, row=q*4+reg — m89-verified) + stats
#pragma unroll
    for (int nt = 0; nt < 4; ++nt) {
        const int col = nt * 16 + m;
        float s = 0.f, s2 = 0.f;
#pragma unroll
        for (int mt = 0; mt < 2; ++mt) {
            const int row0 = base + wv * 32 + mt * 16 + q * 4;
#pragma unroll
            for (int i = 0; i < 4; ++i) {
                const float v = acc[mt][nt][i];
                s += v;
                s2 += v * v;
                out[(size_t)(row0 + i) * 64 + col] = v;
            }
        }
        atomicAdd(&cstat[col], s);
        atomicAdd(&cstat[64 + col], s2);
    }
    __syncthreads();
    if (tid < 128) atomicAdd(&sums[tid], cstat[tid]);
}

__global__ void bn_apply(float* __restrict__ out, const float* __restrict__ sums,
                         const float* __restrict__ gamma,
                         const float* __restrict__ beta) {
    __shared__ float sc[64];
    __shared__ float sh[64];
    const int tid = threadIdx.x;
    if (tid < 64) {
        const float inv_n = 1.0f / (float)NVOX;
        const float mean = sums[tid] * inv_n;
        const float var  = sums[64 + tid] * inv_n - mean * mean;
        const float g    = gamma[tid] * rsqrtf(var + EPS_);
        sc[tid] = g;
        sh[tid] = beta[tid] - mean * g;
    }
    __syncthreads();
    const int cg = (tid & 15) * 4;
    floatx4 scale, shift;
#pragma unroll
    for (int j = 0; j < 4; ++j) {
        scale[j] = sc[cg + j];
        shift[j] = sh[cg + j];
    }
    floatx4* p = (floatx4*)out;
    const int total4 = NVOX * 16;
    for (int i = blockIdx.x * 256 + tid; i < total4; i += gridDim.x * 256) {
        floatx4 v = p[i] * scale + shift;
#pragma unroll
        for (int j = 0; j < 4; ++j) v[j] = v[j] > 0.f ? v[j] : 0.f;
        p[i] = v;
    }
}

extern "C" void kernel_launch(void* const* d_in, const int* in_sizes, int n_in,
                              void* d_out, int out_size, void* d_ws, size_t ws_size,
                              hipStream_t stream) {
    const float* feat  = (const float*)d_in[0];
    const int*   nmap  = (const int*)d_in[1];
    const float* w     = (const float*)d_in[2];
    const float* gamma = (const float*)d_in[3];
    const float* beta  = (const float*)d_in[4];
    float* out = (float*)d_out;

    const size_t FEATB = (size_t)NVOX * 64 * 2;      // 51,200,000
    const size_t WTB   = (size_t)K27 * 64 * 64 * 2;  //    221,184
    const int conv_blocks = NVOX / 128;              // 3125 exactly

    if (ws_size >= FEATB + WTB + 512) {
        unsigned short* feat_bf = (unsigned short*)d_ws;
        unsigned short* wt      = (unsigned short*)((char*)d_ws + FEATB);
        float* sums             = (float*)((char*)d_ws + FEATB + WTB);
        prep_kernel<<<dim3(3158), dim3(256), 0, stream>>>(
            w, feat, feat_bf, wt, sums, 3125);
        conv_mfma<true><<<dim3(conv_blocks), dim3(256), 0, stream>>>(
            feat, feat_bf, nmap, wt, out, sums);
        bn_apply<<<dim3(1024), dim3(256), 0, stream>>>(out, sums, gamma, beta);
    } else {
        // fallback: fp32 gather + in-register pack (no feature buffer)
        unsigned short* wt = (unsigned short*)d_ws;
        float* sums        = (float*)((char*)d_ws + WTB);
        prep_kernel<<<dim3(33), dim3(256), 0, stream>>>(
            w, feat, nullptr, wt, sums, 0);
        conv_mfma<false><<<dim3(conv_blocks), dim3(256), 0, stream>>>(
            feat, nullptr, nmap, wt, out, sums);
        bn_apply<<<dim3(1024), dim3(256), 0, stream>>>(out, sums, gamma, beta);
    }
}

// Round 2
// 444.032 us; speedup vs baseline: 1.3446x; 1.3446x over previous
//
#include <hip/hip_runtime.h>

#define NVOX 400000
#define K27 27
#define EPS_ 1e-5f

typedef short short8 __attribute__((ext_vector_type(8)));
typedef float floatx4 __attribute__((ext_vector_type(4)));
typedef unsigned int uintx4 __attribute__((ext_vector_type(4)));

// round-to-nearest-even fp32 -> bf16, packed pair (a low 16, b high 16)
__device__ __forceinline__ unsigned int pack2bf(float a, float b) {
    unsigned int ua = __builtin_bit_cast(unsigned int, a);
    unsigned int ub = __builtin_bit_cast(unsigned int, b);
    ua += 0x7fffu + ((ua >> 16) & 1u);
    ub += 0x7fffu + ((ub >> 16) & 1u);
    return (ua >> 16) | (ub & 0xffff0000u);
}

// async 16B global->LDS (direct, no VGPR round-trip)
__device__ __forceinline__ void gload_lds16(const void* g, void* l) {
    __builtin_amdgcn_global_load_lds(
        (const __attribute__((address_space(1))) void*)g,
        (__attribute__((address_space(3))) void*)l, 16, 0, 0);
}

// blocks [0, fb): fp32->bf16 feature conversion (32 elems/thread)
// blocks [fb, fb+32): W[k][ci][co] -> wt[k][co][ci] bf16
// block  fb+32: zero the 128 stats accumulators + the zero-row
__global__ void prep_kernel(const float* __restrict__ w,
                            const float* __restrict__ feat,
                            unsigned short* __restrict__ feat_bf,
                            unsigned short* __restrict__ wt,
                            float* __restrict__ sums,
                            float* __restrict__ zrow,
                            int fb) {
    const int b = blockIdx.x;
    const int t = threadIdx.x;
    if (b < fb) {
#pragma unroll
        for (int r = 0; r < 4; ++r) {
            const int i0 = b * 8192 + r * 2048 + t * 8;
            const floatx4* s = (const floatx4*)(feat + i0);
            const floatx4 f0 = s[0], f1 = s[1];
            uintx4 v;
            v[0] = pack2bf(f0[0], f0[1]); v[1] = pack2bf(f0[2], f0[3]);
            v[2] = pack2bf(f1[0], f1[1]); v[3] = pack2bf(f1[2], f1[3]);
            *(uintx4*)(feat_bf + i0) = v;
        }
    } else if (b < fb + 32) {
        for (int g = (b - fb) * 256 + t; g < K27 * 64 * 64; g += 32 * 256) {
            const int k = g >> 12, r = g & 4095, co = r >> 6, ci = r & 63;
            unsigned int u =
                __builtin_bit_cast(unsigned int, w[(k << 12) + (ci << 6) + co]);
            u += 0x7fffu + ((u >> 16) & 1u);
            wt[g] = (unsigned short)(u >> 16);
        }
    } else {
        if (t < 128) sums[t] = 0.0f;
        else if (zrow && t < 136) zrow[t - 128] = 0.0f;
    }
}

// 128 rows x 64 out-ch per block (3125 blocks). 4 waves, wave tile M=32 x
// N=64 -> 2x4 mfma_f32_16x16x32_bf16 per kb (acc 32 AGPR).
//
// R8: R6's LDS double-buffer structure with the two real costs removed.
// (R7 post-mortem: direct-to-fragment reg double-buffering needs 96+ VGPRs
// of fragments; compiler reported 68 VGPRs -> it sank the prefetch loads
// to their uses, destroying the pipeline, and per-wave B re-reads were
// L1-bound. LDS staging is correct; R6's costs were the 2 barriers/k-step
// and the VALU-heavy reg staging.)
//  * global_load_lds width=16 for A and B: no VGPR round-trip, no staging
//    VALU. LDS dest is linear (wave-uniform base + lane*16, m104); the
//    XOR chunk swizzle is applied to the per-lane GLOBAL source instead
//    (guideline 21), so the read side keeps R6's proven conflict-free
//    pattern: slot (row, cs) holds chunk gc = cs ^ (row&7).
//  * Inactive (row,k): source redirected to a 16B zero-row in the
//    workspace -> zeros are staged; no masking or idx reads at compute.
//  * T3 minimum 2-phase: per k-step, issue async loads for k+1 into
//    buf^1, compute k from buf, then ONE __syncthreads (vmcnt(0) drain
//    lands after compute -> gather latency hides under the 16 MFMAs and
//    the other resident waves). 27 barriers/block instead of 54.
//  * idx_lds dropped (each nmap value is consumed exactly once in
//    staging): LDS = 48.5 KB -> 3 blocks/CU.
//  * bijective XCD-chunked block remap (m204) for gather L2 locality.
template <bool BF16FEAT>
__launch_bounds__(256)
__global__ void conv_mfma(const float* __restrict__ feat,
                          const unsigned short* __restrict__ feat_bf,
                          const int* __restrict__ nmap,
                          const unsigned short* __restrict__ wt,
                          const unsigned short* __restrict__ zrow,
                          float* __restrict__ out,
                          float* __restrict__ sums) {
    __shared__ __align__(16) unsigned short a_tile[2][128 * 64];  // 2x16 KB
    __shared__ __align__(16) unsigned short b_tile[2][64 * 64];   // 2x 8 KB
    __shared__ float cstat[128];

    const int tid  = threadIdx.x;
    const int wv   = tid >> 6;
    const int lane = tid & 63;
    const int m    = lane & 15;
    const int q    = lane >> 4;

    // bijective XCD-chunked remap (m204): each XCD gets a contiguous range
    const int nwg = gridDim.x;
    const int q8 = nwg >> 3, r8 = nwg & 7;
    const int xcd = blockIdx.x & 7, lin = blockIdx.x >> 3;
    const int wg =
        (xcd < r8 ? xcd * (q8 + 1) : r8 * (q8 + 1) + (xcd - r8) * q8) + lin;
    const int base = wg * 128;

    if (tid < 128) cstat[tid] = 0.0f;

    int row_a[2];
#pragma unroll
    for (int mt = 0; mt < 2; ++mt) row_a[mt] = wv * 32 + mt * 16 + m;

    floatx4 acc[2][4];
#pragma unroll
    for (int mt = 0; mt < 2; ++mt)
#pragma unroll
        for (int nt = 0; nt < 4; ++nt)
            acc[mt][nt] = (floatx4){0.f, 0.f, 0.f, 0.f};

// issue async staging of tile kk into buffer bufidx (A: 16 wave-issues of
// 1 KB; B: 8). slot s=(j*4+wv)*64+lane -> row=s>>3, slot-col=lane&7; the
// source chunk fetched is gc = (lane&7) ^ (row&7) so the READ-side XOR
// retrieves chunk kb*4+q. Inactive rows read the zero-row.
#define STAGE_G(bufidx, kk)                                                   \
    do {                                                                      \
        _Pragma("unroll") for (int j = 0; j < 4; ++j) {                       \
            const int blk = j * 4 + wv;                                       \
            const int row = blk * 8 + (lane >> 3);                            \
            const int gc  = (lane & 7) ^ (row & 7);                           \
            const int ix  = nmap[(size_t)(kk) * NVOX + base + row];           \
            const unsigned short* src =                                       \
                (ix >= 0) ? feat_bf + (size_t)ix * 64 + gc * 8 : zrow;        \
            gload_lds16(src, a_tile[bufidx] + blk * 512);                     \
        }                                                                     \
        _Pragma("unroll") for (int j = 0; j < 2; ++j) {                       \
            const int blk = j * 4 + wv;                                       \
            const int row = blk * 8 + (lane >> 3);                            \
            const int gc  = (lane & 7) ^ (row & 7);                           \
            gload_lds16(wt + (kk)*4096 + row * 64 + gc * 8,                   \
                        b_tile[bufidx] + blk * 512);                          \
        }                                                                     \
    } while (0)

#define COMPUTE(bufidx)                                                       \
    do {                                                                      \
        _Pragma("unroll") for (int kb = 0; kb < 2; ++kb) {                    \
            short8 af[2], bf[4];                                              \
            _Pragma("unroll") for (int mt = 0; mt < 2; ++mt)                  \
                af[mt] = *(const short8*)(                                    \
                    a_tile[bufidx] +                                          \
                    (row_a[mt] * 8 + ((kb * 4 + q) ^ (row_a[mt] & 7))) * 8);  \
            _Pragma("unroll") for (int nt = 0; nt < 4; ++nt) {                \
                const int row = nt * 16 + m;                                  \
                bf[nt] = *(const short8*)(                                    \
                    b_tile[bufidx] +                                          \
                    (row * 8 + ((kb * 4 + q) ^ (row & 7))) * 8);              \
            }                                                                 \
            _Pragma("unroll") for (int mt = 0; mt < 2; ++mt)                  \
                _Pragma("unroll") for (int nt = 0; nt < 4; ++nt)              \
                    acc[mt][nt] = __builtin_amdgcn_mfma_f32_16x16x32_bf16(    \
                        af[mt], bf[nt], acc[mt][nt], 0, 0, 0);                \
        }                                                                     \
    } while (0)

    if constexpr (BF16FEAT) {
        __syncthreads();  // cstat init visible (cheap; also orders nothing else)
        STAGE_G(0, 0);
        __syncthreads();  // drain tile 0
        for (int kk = 0; kk < K27; kk += 2) {
            if (kk + 1 < K27) STAGE_G(1, kk + 1);  // async into buf1
            COMPUTE(0);                            // tile kk from buf0
            __syncthreads();                       // drain kk+1, reads done
            if (kk + 1 >= K27) break;
            if (kk + 2 < K27) STAGE_G(0, kk + 2);
            COMPUTE(1);
            __syncthreads();
        }
    } else {
        // fallback: fp32 gather + in-register pack, single-buffered staging
        for (int kk = 0; kk < K27; ++kk) {
            short8 areg[4], breg[2];
            int arow[4];
#pragma unroll
            for (int j = 0; j < 4; ++j) {
                const int c = tid + 256 * j;
                arow[j] = c >> 3;
                const int gcs = c & 7;
                const int ix = nmap[(size_t)kk * NVOX + base + arow[j]];
                areg[j] = (short8){0, 0, 0, 0, 0, 0, 0, 0};
                if (ix >= 0) {
                    const float* fp = feat + (size_t)ix * 64 + gcs * 8;
                    const floatx4 f0 = *(const floatx4*)fp;
                    const floatx4 f1 = *(const floatx4*)(fp + 4);
                    uintx4 v;
                    v[0] = pack2bf(f0[0], f0[1]); v[1] = pack2bf(f0[2], f0[3]);
                    v[2] = pack2bf(f1[0], f1[1]); v[3] = pack2bf(f1[2], f1[3]);
                    areg[j] = __builtin_bit_cast(short8, v);
                }
            }
#pragma unroll
            for (int j = 0; j < 2; ++j) {
                const int c = tid + 256 * j;
                breg[j] = *(const short8*)(wt + kk * 4096 + c * 8);
            }
            __syncthreads();  // previous iter's reads done
#pragma unroll
            for (int j = 0; j < 4; ++j) {
                const int c = tid + 256 * j;
                *(short8*)(a_tile[0] +
                           (arow[j] * 8 + ((c & 7) ^ (arow[j] & 7))) * 8) =
                    areg[j];
            }
#pragma unroll
            for (int j = 0; j < 2; ++j) {
                const int c = tid + 256 * j;
                const int br = c >> 3;
                *(short8*)(b_tile[0] + (br * 8 + ((c & 7) ^ (br & 7))) * 8) =
                    breg[j];
            }
            __syncthreads();
            COMPUTE(0);
        }
    }
#undef STAGE_G
#undef COMPUTE

    // epilogue: store (C/D: col=lane&15, row=q*4+reg — m89-verified) + stats
#pragma unroll
    for (int nt = 0; nt < 4; ++nt) {
        const int col = nt * 16 + m;
        float s = 0.f, s2 = 0.f;
#pragma unroll
        for (int mt = 0; mt < 2; ++mt) {
            const int row0 = base + wv * 32 + mt * 16 + q * 4;
#pragma unroll
            for (int i = 0; i < 4; ++i) {
                const float v = acc[mt][nt][i];
                s += v;
                s2 += v * v;
                out[(size_t)(row0 + i) * 64 + col] = v;
            }
        }
        atomicAdd(&cstat[col], s);
        atomicAdd(&cstat[64 + col], s2);
    }
    __syncthreads();
    if (tid < 128) atomicAdd(&sums[tid], cstat[tid]);
}

__global__ void bn_apply(float* __restrict__ out, const float* __restrict__ sums,
                         const float* __restrict__ gamma,
                         const float* __restrict__ beta) {
    __shared__ float sc[64];
    __shared__ float sh[64];
    const int tid = threadIdx.x;
    if (tid < 64) {
        const float inv_n = 1.0f / (float)NVOX;
        const float mean = sums[tid] * inv_n;
        const float var  = sums[64 + tid] * inv_n - mean * mean;
        const float g    = gamma[tid] * rsqrtf(var + EPS_);
        sc[tid] = g;
        sh[tid] = beta[tid] - mean * g;
    }
    __syncthreads();
    const int cg = (tid & 15) * 4;
    floatx4 scale, shift;
#pragma unroll
    for (int j = 0; j < 4; ++j) {
        scale[j] = sc[cg + j];
        shift[j] = sh[cg + j];
    }
    floatx4* p = (floatx4*)out;
    const int total4 = NVOX * 16;
    for (int i = blockIdx.x * 256 + tid; i < total4; i += gridDim.x * 256) {
        floatx4 v = p[i] * scale + shift;
#pragma unroll
        for (int j = 0; j < 4; ++j) v[j] = v[j] > 0.f ? v[j] : 0.f;
        p[i] = v;
    }
}

extern "C" void kernel_launch(void* const* d_in, const int* in_sizes, int n_in,
                              void* d_out, int out_size, void* d_ws, size_t ws_size,
                              hipStream_t stream) {
    const float* feat  = (const float*)d_in[0];
    const int*   nmap  = (const int*)d_in[1];
    const float* w     = (const float*)d_in[2];
    const float* gamma = (const float*)d_in[3];
    const float* beta  = (const float*)d_in[4];
    float* out = (float*)d_out;

    const size_t FEATB = (size_t)NVOX * 64 * 2;      // 51,200,000
    const size_t WTB   = (size_t)K27 * 64 * 64 * 2;  //    221,184
    const int conv_blocks = NVOX / 128;              // 3125 exactly

    if (ws_size >= FEATB + WTB + 512 + 128) {
        unsigned short* feat_bf = (unsigned short*)d_ws;
        unsigned short* wt      = (unsigned short*)((char*)d_ws + FEATB);
        float* sums             = (float*)((char*)d_ws + FEATB + WTB);
        float* zrow             = (float*)((char*)d_ws + FEATB + WTB + 512);
        prep_kernel<<<dim3(3158), dim3(256), 0, stream>>>(
            w, feat, feat_bf, wt, sums, zrow, 3125);
        conv_mfma<true><<<dim3(conv_blocks), dim3(256), 0, stream>>>(
            feat, feat_bf, nmap, wt, (const unsigned short*)zrow, out, sums);
        bn_apply<<<dim3(1024), dim3(256), 0, stream>>>(out, sums, gamma, beta);
    } else {
        // fallback: fp32 gather + in-register pack (no feature buffer)
        unsigned short* wt = (unsigned short*)d_ws;
        float* sums        = (float*)((char*)d_ws + WTB);
        prep_kernel<<<dim3(33), dim3(256), 0, stream>>>(
            w, feat, nullptr, wt, sums, nullptr, 0);
        conv_mfma<false><<<dim3(conv_blocks), dim3(256), 0, stream>>>(
            feat, nullptr, nmap, wt, nullptr, out, sums);
        bn_apply<<<dim3(1024), dim3(256), 0, stream>>>(out, sums, gamma, beta);
    }
}